// Round 17
// baseline (188.973 us; speedup 1.0000x reference)
//
#include <hip/hip_runtime.h>
#include <hip/hip_fp16.h>

// ---- bucket-sort CSR parameters (n <= 131072, so src/dst fit in 17 bits) ----
#define NPB_SHIFT 7
#define NPB       128      // nodes per bucket
#define CHUNK     8192     // edges per hist/scatter block (16 per 512-thread)
#define STAGE_CAP 8192     // bucket_build LDS staging (ints); avg bucket ~4092
#define NBKT_MAX  1024     // LDS bin cap (needs nbkt <= 1024)

union U2H { unsigned u; __half2 h; };

__device__ inline float2 h2f(unsigned u) {
    U2H c; c.u = u;
    return __half22float2(c.h);
}

__device__ inline unsigned f2h(float a, float b) {
    U2H c; c.h = __float22half2_rn(make_float2(a, b));
    return c.u;
}

// ---------------- pass 1: per-block LDS histogram of dst buckets (512 threads) ----------------

__global__ void hist_kernel(const int* __restrict__ dst, int* __restrict__ hist,
                            int E, int HBr, int nbkt) {
    __shared__ int bins[NBKT_MAX];
    int tid = threadIdx.x;
    for (int i = tid; i < nbkt; i += 512) bins[i] = 0;
    __syncthreads();
    int start = blockIdx.x * CHUNK;
    #pragma unroll
    for (int j = 0; j < 16; ++j) {
        int e = start + j * 512 + tid;
        if (e < E) atomicAdd(&bins[dst[e] >> NPB_SHIFT], 1);
    }
    __syncthreads();
    for (int i = tid; i < nbkt; i += 512)
        hist[(size_t)i * HBr + blockIdx.x] = bins[i];
}

// ---------------- block-local exclusive scan over hist matrix (in place) ----------------
// partial[] keeps RAW block totals; consumers scan them inline (<=64 blocks).

__global__ void scan_block8_kernel(int* data, int* __restrict__ partial, int len) {
    __shared__ int wtot[16];
    int tid = threadIdx.x, lane = tid & 63, wid = tid >> 6;
    int base = blockIdx.x * 8192 + tid * 8;
    int v[8]; int s = 0;
    #pragma unroll
    for (int j = 0; j < 8; ++j) {
        int i = base + j;
        v[j] = (i < len) ? data[i] : 0;
        s += v[j];
    }
    int inc = s;
    #pragma unroll
    for (int o = 1; o < 64; o <<= 1) { int t = __shfl_up(inc, o); if (lane >= o) inc += t; }
    if (lane == 63) wtot[wid] = inc;
    __syncthreads();
    if (tid == 0) {
        int run = 0;
        #pragma unroll
        for (int w = 0; w < 16; ++w) { int t = wtot[w]; wtot[w] = run; run += t; }
        partial[blockIdx.x] = run;   // raw block total
    }
    __syncthreads();
    int excl = wtot[wid] + inc - s;
    #pragma unroll
    for (int j = 0; j < 8; ++j) {
        int i = base + j;
        if (i < len) data[i] = excl;
        excl += v[j];
    }
}

// ---------------- pass 2: tile-sort scatter into bucket-ordered ebuf (512 threads) ----------
// payload packed: (dst & 127) << 17 | src   (src < 2^17)
// global offsets = offbuf[..] + psum[idx>>13]; psum = inline exclusive scan of partial[0..nbp)

__global__ void scatter_kernel(const int* __restrict__ src, const int* __restrict__ dst,
                               const int* __restrict__ offbuf, const int* __restrict__ partial,
                               int* __restrict__ ebuf, int E, int HBr, int nbkt, int nbp) {
    __shared__ int psum[64];
    __shared__ int gbase[NBKT_MAX];
    __shared__ int thist[NBKT_MAX];
    __shared__ int toff[NBKT_MAX + 1];
    __shared__ int stage[CHUNK];
    __shared__ unsigned short bstage[CHUNK];
    __shared__ int wtot8[8];
    int tid = threadIdx.x, lane = tid & 63, wid = tid >> 6;
    if (tid < 64) {
        int v = (tid < nbp) ? partial[tid] : 0;
        int inc = v;
        #pragma unroll
        for (int o = 1; o < 64; o <<= 1) { int t = __shfl_up(inc, o); if (tid >= o) inc += t; }
        psum[tid] = inc - v;   // exclusive
    }
    for (int i = tid; i < NBKT_MAX; i += 512) thist[i] = 0;
    __syncthreads();
    for (int i = tid; i < nbkt; i += 512) {
        size_t idx = (size_t)i * HBr + blockIdx.x;
        gbase[i] = offbuf[idx] + psum[(int)(idx >> 13)];
    }
    int start = blockIdx.x * CHUNK;
    int s_[16], d_[16], r_[16];
    #pragma unroll
    for (int j = 0; j < 16; ++j) {
        int e = start + j * 512 + tid;
        if (e < E) {
            s_[j] = src[e];
            d_[j] = dst[e];
            r_[j] = atomicAdd(&thist[d_[j] >> NPB_SHIFT], 1);
        } else {
            d_[j] = -1;
        }
    }
    __syncthreads();
    // exclusive scan of thist[0..1023]: 512 threads x 2 bins
    int a0 = thist[2 * tid], a1 = thist[2 * tid + 1];
    int ss = a0 + a1;
    int inc = ss;
    #pragma unroll
    for (int o = 1; o < 64; o <<= 1) { int t = __shfl_up(inc, o); if (lane >= o) inc += t; }
    if (lane == 63) wtot8[wid] = inc;
    __syncthreads();
    int wbase = 0;
    for (int w = 0; w < wid; ++w) wbase += wtot8[w];
    int excl = wbase + inc - ss;
    toff[2 * tid]     = excl;
    toff[2 * tid + 1] = excl + a0;
    if (tid == 511) toff[1024] = excl + ss;  // total valid
    __syncthreads();
    #pragma unroll
    for (int j = 0; j < 16; ++j) {
        if (d_[j] >= 0) {
            int b = d_[j] >> NPB_SHIFT;
            int q = toff[b] + r_[j];
            stage[q]  = ((d_[j] & (NPB - 1)) << 17) | s_[j];
            bstage[q] = (unsigned short)b;
        }
    }
    __syncthreads();
    int total = toff[1024];
    for (int j = tid; j < total; j += 512) {
        int b = bstage[j];
        ebuf[gbase[b] + (j - toff[b])] = stage[j];
    }
}

// ---------------- pass 3: per-bucket CSR build + row_start + dinv + fused pad_scale (fp16) --

__global__ void bucket_build_kernel(const int* __restrict__ ebuf, const int* __restrict__ offbuf,
                                    const int* __restrict__ partial, const float* __restrict__ x,
                                    int* __restrict__ csr_src, int* __restrict__ row_start,
                                    float* __restrict__ dinv, unsigned* __restrict__ g0h,
                                    int E, int HBr, int nbkt, int n, int nbp) {
    __shared__ int psum[64];
    __shared__ int cnt[NPB], cur[NPB];
    __shared__ float dnl[NPB];
    __shared__ int stage[STAGE_CAP];
    __shared__ int wtot2[2];
    int tid = threadIdx.x;
    int k = blockIdx.x;
    if (tid < 64) {
        int v = (tid < nbp) ? partial[tid] : 0;
        int inc = v;
        #pragma unroll
        for (int o = 1; o < 64; o <<= 1) { int t = __shfl_up(inc, o); if (tid >= o) inc += t; }
        psum[tid] = inc - v;   // exclusive
    }
    if (tid < NPB) cnt[tid] = 0;
    __syncthreads();

    size_t ib = (size_t)k * HBr;
    int bb = offbuf[ib] + psum[(int)(ib >> 13)];
    int be;
    if (k + 1 < nbkt) {
        size_t ie = (size_t)(k + 1) * HBr;
        be = offbuf[ie] + psum[(int)(ie >> 13)];
    } else be = E;
    int bsize = be - bb;

    constexpr int J = 20;                       // 20*256 = 5120 edge cap (avg 4092)
    int v[J], r[J];
    bool fast = (bsize <= J * 256) && (bsize <= STAGE_CAP);
    if (fast) {
        #pragma unroll
        for (int j = 0; j < J; ++j) {
            int e = bb + tid + j * 256;
            if (e < be) { v[j] = ebuf[e]; r[j] = atomicAdd(&cnt[v[j] >> 17], 1); }
            else v[j] = -1;
        }
    } else {
        for (int e = bb + tid; e < be; e += 256) atomicAdd(&cnt[ebuf[e] >> 17], 1);
    }
    __syncthreads();

    int lane = tid & 63, wid = tid >> 6;
    int c = 0, inc = 0;
    if (tid < NPB) {
        c = cnt[tid];
        inc = c;
        #pragma unroll
        for (int o = 1; o < 64; o <<= 1) { int t = __shfl_up(inc, o); if (lane >= o) inc += t; }
        if (lane == 63) wtot2[wid] = inc;
    }
    __syncthreads();
    if (tid < NPB) {
        int base = (wid == 1) ? wtot2[0] : 0;
        int excl = base + inc - c;
        cur[tid] = excl;
        int node = k * NPB + tid;
        if (node < n) {
            row_start[node] = bb + excl;
            float dn = rsqrtf((float)(c + 1));  // self-loop
            dinv[node] = dn;
            dnl[tid] = dn;
        }
    }
    if (k == 0 && tid == 0) row_start[n] = E;
    __syncthreads();

    // fused pad_scale into fp16: g0[node] = half(pad16(x[node]) * dinv[node])
    {
        int base_node = k * NPB;
        for (int i = tid; i < NPB * 8; i += 256) {
            int ln = i >> 3, kk = i & 7;
            int node = base_node + ln;
            if (node < n) {
                float dn = dnl[ln];
                int f0 = 2 * kk, f1 = f0 + 1;
                float a = (f0 < 11) ? x[(size_t)node * 11 + f0] * dn : 0.f;
                float b = (f1 < 11) ? x[(size_t)node * 11 + f1] * dn : 0.f;
                g0h[(size_t)node * 8 + kk] = f2h(a, b);
            }
        }
    }

    if (fast) {
        #pragma unroll
        for (int j = 0; j < J; ++j)
            if (v[j] >= 0) stage[cur[v[j] >> 17] + r[j]] = v[j] & 0x1FFFF;
        __syncthreads();
        for (int j = tid; j < bsize; j += 256) csr_src[bb + j] = stage[j];  // coalesced
    } else if (bsize <= STAGE_CAP) {
        for (int e = bb + tid; e < be; e += 256) {
            int vv = ebuf[e];
            int rr = atomicAdd(&cur[vv >> 17], 1);
            stage[rr] = vv & 0x1FFFF;
        }
        __syncthreads();
        for (int j = tid; j < bsize; j += 256) csr_src[bb + j] = stage[j];
    } else {
        for (int e = bb + tid; e < be; e += 256) {
            int vv = ebuf[e];
            int rr = atomicAdd(&cur[vv >> 17], 1);
            csr_src[bb + rr] = vv & 0x1FFFF;
        }
    }
}

// ---------------- gather-aggregate over fp16 tables: 4 nodes per wave ----------------
// pre[d] = dinv[d] * (sum_{s in N(d)} g[s] + g[d]);  g rows carry dinv[s], stored fp16.
// 16-lane sub-wave per node: LPR lanes/row (uint2 = 4 halves each), NGRP=16/LPR rows
// per instruction per sub-wave. Output: pre[node*s4 + off4 + q] (float4 units) so
// feature-split passes can write halves of a wider row.

template <int LPR, int NB>
__device__ inline void gather_batch_h(const uint2* __restrict__ gv, const int* __restrict__ csr,
                                      int p, int end, int nrem, int q, int grp, float* acc) {
    constexpr int NGRP = 16 / LPR;
    int s[NB]; float m[NB];
    #pragma unroll
    for (int u = 0; u < NB; ++u) {
        int slot = u * NGRP + grp;
        s[u] = csr[min(p + slot, end - 1)];               // clamped, in-bounds
        m[u] = (slot < nrem) ? 1.f : 0.f;
    }
    uint2 v[NB];
    #pragma unroll
    for (int u = 0; u < NB; ++u) v[u] = gv[(size_t)s[u] * LPR + q];
    #pragma unroll
    for (int u = 0; u < NB; ++u) {
        float2 a = h2f(v[u].x), b = h2f(v[u].y);
        acc[0] = fmaf(m[u], a.x, acc[0]);
        acc[1] = fmaf(m[u], a.y, acc[1]);
        acc[2] = fmaf(m[u], b.x, acc[2]);
        acc[3] = fmaf(m[u], b.y, acc[3]);
    }
}

template <int FIN>
__global__ void aggregate_kernel(const uint2* __restrict__ gv,
                                 const int* __restrict__ row_start,
                                 const int* __restrict__ csr_src,
                                 const float* __restrict__ dinv,
                                 float4* __restrict__ pre, int n, int s4, int off4) {
    constexpr int LPR  = FIN / 4;   // lanes per row (4 or 8)
    constexpr int NGRP = 16 / LPR;  // rows per instruction per sub-wave (4 or 2)
    int lane  = threadIdx.x & 63;
    int wid   = threadIdx.x >> 6;
    int sub   = lane >> 4;          // sub-wave 0..3
    int slane = lane & 15;
    int node  = (blockIdx.x * (blockDim.x >> 6) + wid) * 4 + sub;
    if (node >= n) return;
    int q   = slane & (LPR - 1);
    int grp = slane / LPR;          // 0..NGRP-1
    int beg = row_start[node];
    int end = row_start[node + 1];
    float acc[4] = {0.f, 0.f, 0.f, 0.f};

    int p = beg;
    // unmasked full batches: 8 instructions = 8*NGRP rows per sub-wave
    for (; p + 8 * NGRP <= end; p += 8 * NGRP) {
        int s[8];
        #pragma unroll
        for (int u = 0; u < 8; ++u) s[u] = csr_src[p + u * NGRP + grp];
        uint2 v[8];
        #pragma unroll
        for (int u = 0; u < 8; ++u) v[u] = gv[(size_t)s[u] * LPR + q];
        #pragma unroll
        for (int u = 0; u < 8; ++u) {
            float2 a = h2f(v[u].x), b = h2f(v[u].y);
            acc[0] += a.x; acc[1] += a.y; acc[2] += b.x; acc[3] += b.y;
        }
    }
    // deg-adaptive masked tail
    int nrem = end - p;
    if (nrem > 0) {
        if (nrem <= NGRP)          gather_batch_h<LPR, 1>(gv, csr_src, p, end, nrem, q, grp, acc);
        else if (nrem <= 2 * NGRP) gather_batch_h<LPR, 2>(gv, csr_src, p, end, nrem, q, grp, acc);
        else if (nrem <= 4 * NGRP) gather_batch_h<LPR, 4>(gv, csr_src, p, end, nrem, q, grp, acc);
        else                       gather_batch_h<LPR, 8>(gv, csr_src, p, end, nrem, q, grp, acc);
    }

    // butterfly-reduce across row groups within the 16-lane sub-wave
    #pragma unroll
    for (int off = LPR; off < 16; off <<= 1)
        #pragma unroll
        for (int c = 0; c < 4; ++c) acc[c] += __shfl_xor(acc[c], off);

    // add self row, scale by dinv[d], vector store by lanes grp==0 of each sub-wave
    float dn = dinv[node];
    uint2 sv = gv[(size_t)node * LPR + q];
    float2 a = h2f(sv.x), b = h2f(sv.y);
    float4 o;
    o.x = dn * (acc[0] + a.x);
    o.y = dn * (acc[1] + a.y);
    o.z = dn * (acc[2] + b.x);
    o.w = dn * (acc[3] + b.y);
    if (grp == 0) pre[(size_t)node * s4 + off4 + q] = o;
}

// ---------------- post-agg linear (thread-per-node) ----------------
// out = [relu](pre @ W + b) [* dinv];  HALFOUT packs to fp16; SPLIT writes the two
// output halves to separate half-tables (outv = features [0,FOUT/2), outv2 = rest).

template <int FINP, int FINR, int FOUT, bool RELU, bool SCALE, bool HALFOUT, bool SPLIT>
__global__ void linear_kernel(const float* __restrict__ pre, const float* __restrict__ W,
                              const float* __restrict__ bias, const float* __restrict__ dinv,
                              void* __restrict__ outv, void* __restrict__ outv2, int n) {
    __shared__ float sW[FINP * FOUT];
    __shared__ float sB[FOUT];
    for (int i = threadIdx.x; i < FINP * FOUT; i += blockDim.x)
        sW[i] = (i < FINR * FOUT) ? W[i] : 0.f;
    for (int i = threadIdx.x; i < FOUT; i += blockDim.x) sB[i] = bias[i];
    __syncthreads();
    int node = blockIdx.x * blockDim.x + threadIdx.x;
    if (node >= n) return;
    float xi[FINP];
    #pragma unroll
    for (int k = 0; k < FINP; ++k) xi[k] = pre[(size_t)node * FINP + k];
    float s = SCALE ? dinv[node] : 1.f;
    float o[FOUT];
    #pragma unroll
    for (int fo = 0; fo < FOUT; ++fo) {
        float acc = sB[fo];
        #pragma unroll
        for (int k = 0; k < FINP; ++k) acc = fmaf(xi[k], sW[k * FOUT + fo], acc);
        if (RELU) acc = fmaxf(acc, 0.f);
        o[fo] = acc * s;
    }
    if constexpr (HALFOUT) {
        if constexpr (SPLIT) {
            unsigned* oa = (unsigned*)outv;
            unsigned* ob = (unsigned*)outv2;
            #pragma unroll
            for (int fo = 0; fo < FOUT / 2; fo += 2)
                oa[(size_t)node * (FOUT / 4) + (fo >> 1)] = f2h(o[fo], o[fo + 1]);
            #pragma unroll
            for (int fo = FOUT / 2; fo < FOUT; fo += 2)
                ob[(size_t)node * (FOUT / 4) + ((fo - FOUT / 2) >> 1)] = f2h(o[fo], o[fo + 1]);
        } else {
            unsigned* outh = (unsigned*)outv;
            #pragma unroll
            for (int fo = 0; fo < FOUT / 2; ++fo)
                outh[(size_t)node * (FOUT / 2) + fo] = f2h(o[2 * fo], o[2 * fo + 1]);
        }
    } else {
        float* outf = (float*)outv;
        #pragma unroll
        for (int fo = 0; fo < FOUT; ++fo) outf[(size_t)node * FOUT + fo] = o[fo];
    }
}

// ---------------- launch ----------------

extern "C" void kernel_launch(void* const* d_in, const int* in_sizes, int n_in,
                              void* d_out, int out_size, void* d_ws, size_t ws_size,
                              hipStream_t stream) {
    const float* x  = (const float*)d_in[0];
    const int*   ei = (const int*)d_in[1];
    const float* W1 = (const float*)d_in[2];
    const float* b1 = (const float*)d_in[3];
    const float* W2 = (const float*)d_in[4];
    const float* b2 = (const float*)d_in[5];
    const float* W3 = (const float*)d_in[6];
    const float* b3 = (const float*)d_in[7];
    float* out = (float*)d_out;

    const int n = in_sizes[0] / 11;   // 100000
    const int E = in_sizes[1] / 2;    // 3200000
    const int* src = ei;
    const int* dst = ei + E;

    const int nbkt = (n + NPB - 1) >> NPB_SHIFT;        // 782
    const int HBr  = (E + CHUNK - 1) / CHUNK;           // 391
    const size_t len = (size_t)nbkt * HBr;              // 305,762
    const int nb = (int)((len + 8191) / 8192);          // 38 (<=64)

    char* ws = (char*)d_ws;
    size_t off = 0;
    auto alloc = [&](size_t bytes) {
        void* p = ws + off;
        off = (off + bytes + 255) & ~(size_t)255;
        return p;
    };
    int*      offbuf    = (int*)     alloc(len * 4);
    int*      partial   = (int*)     alloc((size_t)128 * 4);
    int*      ebuf      = (int*)     alloc((size_t)E * 4);
    int*      csr_src   = (int*)     alloc((size_t)E * 4);
    int*      row_start = (int*)     alloc((size_t)(n + 1) * 4);
    float*    dinv      = (float*)   alloc((size_t)n * 4);
    unsigned* g0h       = (unsigned*)alloc((size_t)n * 16 * 2);   // fp16 tables (3.2 MB each)
    unsigned* g1h       = (unsigned*)alloc((size_t)n * 16 * 2);
    unsigned* g2a       = (unsigned*)alloc((size_t)n * 16 * 2);   // layer-3 features 0..15
    unsigned* g2b       = (unsigned*)alloc((size_t)n * 16 * 2);   // layer-3 features 16..31
    float*    preS      = (float*)   alloc((size_t)n * 16 * 4);   // pre1 / pre2
    float*    preL      = (float*)   alloc((size_t)n * 32 * 4);   // pre3
    (void)ws_size;

    const int B = 256;
    int gn   = (n + B - 1) / B;
    int gagg = (n + 15) / 16;         // 4 waves/block x 4 nodes/wave

    // ---- atomic-free CSR build (+ fused dinv/row_start/pad_scale->fp16) ----
    hist_kernel<<<HBr, 512, 0, stream>>>(dst, offbuf, E, HBr, nbkt);
    scan_block8_kernel<<<nb, 1024, 0, stream>>>(offbuf, partial, (int)len);
    scatter_kernel<<<HBr, 512, 0, stream>>>(src, dst, offbuf, partial, ebuf, E, HBr, nbkt, nb);
    bucket_build_kernel<<<nbkt, 256, 0, stream>>>(ebuf, offbuf, partial, x, csr_src, row_start,
                                                  dinv, g0h, E, HBr, nbkt, n, nb);

    // layer 1: agg(16-wide fp16) -> linear 11->16, relu, scale -> fp16 table
    aggregate_kernel<16><<<gagg, B, 0, stream>>>((const uint2*)g0h, row_start, csr_src, dinv,
                                                 (float4*)preS, n, 4, 0);
    linear_kernel<16, 11, 16, true, true, true, false>
        <<<gn, B, 0, stream>>>(preS, W1, b1, dinv, g1h, nullptr, n);

    // layer 2: agg(16 fp16) -> linear 16->32, relu, scale -> two fp16 half-tables
    aggregate_kernel<16><<<gagg, B, 0, stream>>>((const uint2*)g1h, row_start, csr_src, dinv,
                                                 (float4*)preS, n, 4, 0);
    linear_kernel<16, 16, 32, true, true, true, true>
        <<<gn, B, 0, stream>>>(preS, W2, b2, dinv, g2a, g2b, n);

    // layer 3: two feature-split aggregate passes (each table 3.2 MB, L2-resident),
    // then linear 32->64, no relu, no scale, fp32 out
    aggregate_kernel<16><<<gagg, B, 0, stream>>>((const uint2*)g2a, row_start, csr_src, dinv,
                                                 (float4*)preL, n, 8, 0);
    aggregate_kernel<16><<<gagg, B, 0, stream>>>((const uint2*)g2b, row_start, csr_src, dinv,
                                                 (float4*)preL, n, 8, 4);
    linear_kernel<32, 32, 64, false, false, false, false>
        <<<gn, B, 0, stream>>>(preL, W3, b3, dinv, out, nullptr, n);
}

// Round 18
// 176.839 us; speedup vs baseline: 1.0686x; 1.0686x over previous
//
#include <hip/hip_runtime.h>
#include <hip/hip_fp16.h>

// ---- bucket-sort CSR parameters (n <= 131072, so src/dst fit in 17 bits) ----
#define NPB_SHIFT 7
#define NPB       128      // nodes per bucket
#define CHUNK     8192     // edges per hist/scatter block (16 per 512-thread)
#define STAGE_CAP 8192     // bucket_build LDS staging (ints); avg bucket ~4092
#define NBKT_MAX  1024     // LDS bin cap (needs nbkt <= 1024)

union U2H { unsigned u; __half2 h; };

__device__ inline float2 h2f(unsigned u) {
    U2H c; c.u = u;
    return __half22float2(c.h);
}

__device__ inline unsigned f2h(float a, float b) {
    U2H c; c.h = __float22half2_rn(make_float2(a, b));
    return c.u;
}

// ---------------- pass 1: per-block LDS histogram of dst buckets (512 threads) ----------------

__global__ void hist_kernel(const int* __restrict__ dst, int* __restrict__ hist,
                            int E, int HBr, int nbkt) {
    __shared__ int bins[NBKT_MAX];
    int tid = threadIdx.x;
    for (int i = tid; i < nbkt; i += 512) bins[i] = 0;
    __syncthreads();
    int start = blockIdx.x * CHUNK;
    #pragma unroll
    for (int j = 0; j < 16; ++j) {
        int e = start + j * 512 + tid;
        if (e < E) atomicAdd(&bins[dst[e] >> NPB_SHIFT], 1);
    }
    __syncthreads();
    for (int i = tid; i < nbkt; i += 512)
        hist[(size_t)i * HBr + blockIdx.x] = bins[i];
}

// ---------------- block-local exclusive scan over hist matrix (in place) ----------------
// partial[] keeps RAW block totals; consumers scan them inline (<=64 blocks).

__global__ void scan_block8_kernel(int* data, int* __restrict__ partial, int len) {
    __shared__ int wtot[16];
    int tid = threadIdx.x, lane = tid & 63, wid = tid >> 6;
    int base = blockIdx.x * 8192 + tid * 8;
    int v[8]; int s = 0;
    #pragma unroll
    for (int j = 0; j < 8; ++j) {
        int i = base + j;
        v[j] = (i < len) ? data[i] : 0;
        s += v[j];
    }
    int inc = s;
    #pragma unroll
    for (int o = 1; o < 64; o <<= 1) { int t = __shfl_up(inc, o); if (lane >= o) inc += t; }
    if (lane == 63) wtot[wid] = inc;
    __syncthreads();
    if (tid == 0) {
        int run = 0;
        #pragma unroll
        for (int w = 0; w < 16; ++w) { int t = wtot[w]; wtot[w] = run; run += t; }
        partial[blockIdx.x] = run;   // raw block total
    }
    __syncthreads();
    int excl = wtot[wid] + inc - s;
    #pragma unroll
    for (int j = 0; j < 8; ++j) {
        int i = base + j;
        if (i < len) data[i] = excl;
        excl += v[j];
    }
}

// ---------------- pass 2: tile-sort scatter into bucket-ordered ebuf (512 threads) ----------
// payload packed: (dst & 127) << 17 | src   (src < 2^17)
// global offsets = offbuf[..] + psum[idx>>13]; psum = inline exclusive scan of partial[0..nbp)

__global__ void scatter_kernel(const int* __restrict__ src, const int* __restrict__ dst,
                               const int* __restrict__ offbuf, const int* __restrict__ partial,
                               int* __restrict__ ebuf, int E, int HBr, int nbkt, int nbp) {
    __shared__ int psum[64];
    __shared__ int gbase[NBKT_MAX];
    __shared__ int thist[NBKT_MAX];
    __shared__ int toff[NBKT_MAX + 1];
    __shared__ int stage[CHUNK];
    __shared__ unsigned short bstage[CHUNK];
    __shared__ int wtot8[8];
    int tid = threadIdx.x, lane = tid & 63, wid = tid >> 6;
    if (tid < 64) {
        int v = (tid < nbp) ? partial[tid] : 0;
        int inc = v;
        #pragma unroll
        for (int o = 1; o < 64; o <<= 1) { int t = __shfl_up(inc, o); if (tid >= o) inc += t; }
        psum[tid] = inc - v;   // exclusive
    }
    for (int i = tid; i < NBKT_MAX; i += 512) thist[i] = 0;
    __syncthreads();
    for (int i = tid; i < nbkt; i += 512) {
        size_t idx = (size_t)i * HBr + blockIdx.x;
        gbase[i] = offbuf[idx] + psum[(int)(idx >> 13)];
    }
    int start = blockIdx.x * CHUNK;
    int s_[16], d_[16], r_[16];
    #pragma unroll
    for (int j = 0; j < 16; ++j) {
        int e = start + j * 512 + tid;
        if (e < E) {
            s_[j] = src[e];
            d_[j] = dst[e];
            r_[j] = atomicAdd(&thist[d_[j] >> NPB_SHIFT], 1);
        } else {
            d_[j] = -1;
        }
    }
    __syncthreads();
    // exclusive scan of thist[0..1023]: 512 threads x 2 bins
    int a0 = thist[2 * tid], a1 = thist[2 * tid + 1];
    int ss = a0 + a1;
    int inc = ss;
    #pragma unroll
    for (int o = 1; o < 64; o <<= 1) { int t = __shfl_up(inc, o); if (lane >= o) inc += t; }
    if (lane == 63) wtot8[wid] = inc;
    __syncthreads();
    int wbase = 0;
    for (int w = 0; w < wid; ++w) wbase += wtot8[w];
    int excl = wbase + inc - ss;
    toff[2 * tid]     = excl;
    toff[2 * tid + 1] = excl + a0;
    if (tid == 511) toff[1024] = excl + ss;  // total valid
    __syncthreads();
    #pragma unroll
    for (int j = 0; j < 16; ++j) {
        if (d_[j] >= 0) {
            int b = d_[j] >> NPB_SHIFT;
            int q = toff[b] + r_[j];
            stage[q]  = ((d_[j] & (NPB - 1)) << 17) | s_[j];
            bstage[q] = (unsigned short)b;
        }
    }
    __syncthreads();
    int total = toff[1024];
    for (int j = tid; j < total; j += 512) {
        int b = bstage[j];
        ebuf[gbase[b] + (j - toff[b])] = stage[j];
    }
}

// ---------------- pass 3: per-bucket CSR build (512 threads) + row_start + dinv + pad_scale --

__global__ void bucket_build_kernel(const int* __restrict__ ebuf, const int* __restrict__ offbuf,
                                    const int* __restrict__ partial, const float* __restrict__ x,
                                    int* __restrict__ csr_src, int* __restrict__ row_start,
                                    float* __restrict__ dinv, unsigned* __restrict__ g0h,
                                    int E, int HBr, int nbkt, int n, int nbp) {
    __shared__ int psum[64];
    __shared__ int cnt[NPB], cur[NPB];
    __shared__ float dnl[NPB];
    __shared__ int stage[STAGE_CAP];
    __shared__ int wtot2[2];
    int tid = threadIdx.x;
    int k = blockIdx.x;
    if (tid < 64) {
        int v = (tid < nbp) ? partial[tid] : 0;
        int inc = v;
        #pragma unroll
        for (int o = 1; o < 64; o <<= 1) { int t = __shfl_up(inc, o); if (tid >= o) inc += t; }
        psum[tid] = inc - v;   // exclusive
    }
    if (tid < NPB) cnt[tid] = 0;
    __syncthreads();

    size_t ib = (size_t)k * HBr;
    int bb = offbuf[ib] + psum[(int)(ib >> 13)];
    int be;
    if (k + 1 < nbkt) {
        size_t ie = (size_t)(k + 1) * HBr;
        be = offbuf[ie] + psum[(int)(ie >> 13)];
    } else be = E;
    int bsize = be - bb;

    constexpr int J = 10;                       // 10*512 = 5120 edge cap (avg 4092)
    int v[J], r[J];
    bool fast = (bsize <= J * 512) && (bsize <= STAGE_CAP);
    if (fast) {
        #pragma unroll
        for (int j = 0; j < J; ++j) {
            int e = bb + tid + j * 512;
            if (e < be) { v[j] = ebuf[e]; r[j] = atomicAdd(&cnt[v[j] >> 17], 1); }
            else v[j] = -1;
        }
    } else {
        for (int e = bb + tid; e < be; e += 512) atomicAdd(&cnt[ebuf[e] >> 17], 1);
    }
    __syncthreads();

    int lane = tid & 63, wid = tid >> 6;
    int c = 0, inc = 0;
    if (tid < NPB) {                            // waves 0,1 entirely inside
        c = cnt[tid];
        inc = c;
        #pragma unroll
        for (int o = 1; o < 64; o <<= 1) { int t = __shfl_up(inc, o); if (lane >= o) inc += t; }
        if (lane == 63) wtot2[wid] = inc;
    }
    __syncthreads();
    if (tid < NPB) {
        int base = (wid == 1) ? wtot2[0] : 0;
        int excl = base + inc - c;
        cur[tid] = excl;
        int node = k * NPB + tid;
        if (node < n) {
            row_start[node] = bb + excl;
            float dn = rsqrtf((float)(c + 1));  // self-loop
            dinv[node] = dn;
            dnl[tid] = dn;
        }
    }
    if (k == 0 && tid == 0) row_start[n] = E;
    __syncthreads();

    // fused pad_scale into fp16: g0[node] = half(pad16(x[node]) * dinv[node])
    {
        int base_node = k * NPB;
        for (int i = tid; i < NPB * 8; i += 512) {
            int ln = i >> 3, kk = i & 7;
            int node = base_node + ln;
            if (node < n) {
                float dn = dnl[ln];
                int f0 = 2 * kk, f1 = f0 + 1;
                float a = (f0 < 11) ? x[(size_t)node * 11 + f0] * dn : 0.f;
                float b = (f1 < 11) ? x[(size_t)node * 11 + f1] * dn : 0.f;
                g0h[(size_t)node * 8 + kk] = f2h(a, b);
            }
        }
    }

    if (fast) {
        #pragma unroll
        for (int j = 0; j < J; ++j)
            if (v[j] >= 0) stage[cur[v[j] >> 17] + r[j]] = v[j] & 0x1FFFF;
        __syncthreads();
        for (int j = tid; j < bsize; j += 512) csr_src[bb + j] = stage[j];  // coalesced
    } else if (bsize <= STAGE_CAP) {
        for (int e = bb + tid; e < be; e += 512) {
            int vv = ebuf[e];
            int rr = atomicAdd(&cur[vv >> 17], 1);
            stage[rr] = vv & 0x1FFFF;
        }
        __syncthreads();
        for (int j = tid; j < bsize; j += 512) csr_src[bb + j] = stage[j];
    } else {
        for (int e = bb + tid; e < be; e += 512) {
            int vv = ebuf[e];
            int rr = atomicAdd(&cur[vv >> 17], 1);
            csr_src[bb + rr] = vv & 0x1FFFF;
        }
    }
}

// ---------------- gather-aggregate over fp16 tables: 4 nodes per wave ----------------
// pre[d] = dinv[d] * (sum_{s in N(d)} g[s] + g[d]);  g rows carry dinv[s], stored fp16.
// 16-lane sub-wave per node: LPR lanes/row (uint2 = 4 halves each), NGRP=16/LPR rows
// per instruction per sub-wave. Four independent chains per wave.

template <int LPR, int NB>
__device__ inline void gather_batch_h(const uint2* __restrict__ gv, const int* __restrict__ csr,
                                      int p, int end, int nrem, int q, int grp, float* acc) {
    constexpr int NGRP = 16 / LPR;
    int s[NB]; float m[NB];
    #pragma unroll
    for (int u = 0; u < NB; ++u) {
        int slot = u * NGRP + grp;
        s[u] = csr[min(p + slot, end - 1)];               // clamped, in-bounds
        m[u] = (slot < nrem) ? 1.f : 0.f;
    }
    uint2 v[NB];
    #pragma unroll
    for (int u = 0; u < NB; ++u) v[u] = gv[(size_t)s[u] * LPR + q];
    #pragma unroll
    for (int u = 0; u < NB; ++u) {
        float2 a = h2f(v[u].x), b = h2f(v[u].y);
        acc[0] = fmaf(m[u], a.x, acc[0]);
        acc[1] = fmaf(m[u], a.y, acc[1]);
        acc[2] = fmaf(m[u], b.x, acc[2]);
        acc[3] = fmaf(m[u], b.y, acc[3]);
    }
}

template <int FIN>
__global__ void aggregate_kernel(const uint2* __restrict__ gv,
                                 const int* __restrict__ row_start,
                                 const int* __restrict__ csr_src,
                                 const float* __restrict__ dinv,
                                 float4* __restrict__ pre, int n) {
    constexpr int LPR  = FIN / 4;   // lanes per row (4 or 8)
    constexpr int NGRP = 16 / LPR;  // rows per instruction per sub-wave (4 or 2)
    int lane  = threadIdx.x & 63;
    int wid   = threadIdx.x >> 6;
    int sub   = lane >> 4;          // sub-wave 0..3
    int slane = lane & 15;
    int node  = (blockIdx.x * (blockDim.x >> 6) + wid) * 4 + sub;
    if (node >= n) return;
    int q   = slane & (LPR - 1);
    int grp = slane / LPR;          // 0..NGRP-1
    int beg = row_start[node];
    int end = row_start[node + 1];
    float acc[4] = {0.f, 0.f, 0.f, 0.f};

    int p = beg;
    // unmasked full batches: 8 instructions = 8*NGRP rows per sub-wave
    for (; p + 8 * NGRP <= end; p += 8 * NGRP) {
        int s[8];
        #pragma unroll
        for (int u = 0; u < 8; ++u) s[u] = csr_src[p + u * NGRP + grp];
        uint2 v[8];
        #pragma unroll
        for (int u = 0; u < 8; ++u) v[u] = gv[(size_t)s[u] * LPR + q];
        #pragma unroll
        for (int u = 0; u < 8; ++u) {
            float2 a = h2f(v[u].x), b = h2f(v[u].y);
            acc[0] += a.x; acc[1] += a.y; acc[2] += b.x; acc[3] += b.y;
        }
    }
    // deg-adaptive masked tail
    int nrem = end - p;
    if (nrem > 0) {
        if (nrem <= NGRP)          gather_batch_h<LPR, 1>(gv, csr_src, p, end, nrem, q, grp, acc);
        else if (nrem <= 2 * NGRP) gather_batch_h<LPR, 2>(gv, csr_src, p, end, nrem, q, grp, acc);
        else if (nrem <= 4 * NGRP) gather_batch_h<LPR, 4>(gv, csr_src, p, end, nrem, q, grp, acc);
        else                       gather_batch_h<LPR, 8>(gv, csr_src, p, end, nrem, q, grp, acc);
    }

    // butterfly-reduce across row groups within the 16-lane sub-wave
    #pragma unroll
    for (int off = LPR; off < 16; off <<= 1)
        #pragma unroll
        for (int c = 0; c < 4; ++c) acc[c] += __shfl_xor(acc[c], off);

    // add self row, scale by dinv[d], vector store by lanes grp==0 of each sub-wave
    float dn = dinv[node];
    uint2 sv = gv[(size_t)node * LPR + q];
    float2 a = h2f(sv.x), b = h2f(sv.y);
    float4 o;
    o.x = dn * (acc[0] + a.x);
    o.y = dn * (acc[1] + a.y);
    o.z = dn * (acc[2] + b.x);
    o.w = dn * (acc[3] + b.y);
    if (grp == 0) pre[(size_t)node * LPR + q] = o;
}

// ---------------- post-agg linear (thread-per-node) ----------------
// out = [relu](pre @ W + b) [* dinv];  HALFOUT packs the result to fp16 pairs.

template <int FINP, int FINR, int FOUT, bool RELU, bool SCALE, bool HALFOUT>
__global__ void linear_kernel(const float* __restrict__ pre, const float* __restrict__ W,
                              const float* __restrict__ bias, const float* __restrict__ dinv,
                              void* __restrict__ outv, int n) {
    __shared__ float sW[FINP * FOUT];
    __shared__ float sB[FOUT];
    for (int i = threadIdx.x; i < FINP * FOUT; i += blockDim.x)
        sW[i] = (i < FINR * FOUT) ? W[i] : 0.f;
    for (int i = threadIdx.x; i < FOUT; i += blockDim.x) sB[i] = bias[i];
    __syncthreads();
    int node = blockIdx.x * blockDim.x + threadIdx.x;
    if (node >= n) return;
    float xi[FINP];
    #pragma unroll
    for (int k = 0; k < FINP; ++k) xi[k] = pre[(size_t)node * FINP + k];
    float s = SCALE ? dinv[node] : 1.f;
    float o[FOUT];
    #pragma unroll
    for (int fo = 0; fo < FOUT; ++fo) {
        float acc = sB[fo];
        #pragma unroll
        for (int k = 0; k < FINP; ++k) acc = fmaf(xi[k], sW[k * FOUT + fo], acc);
        if (RELU) acc = fmaxf(acc, 0.f);
        o[fo] = acc * s;
    }
    if constexpr (HALFOUT) {
        unsigned* outh = (unsigned*)outv;
        #pragma unroll
        for (int fo = 0; fo < FOUT / 2; ++fo)
            outh[(size_t)node * (FOUT / 2) + fo] = f2h(o[2 * fo], o[2 * fo + 1]);
    } else {
        float* outf = (float*)outv;
        #pragma unroll
        for (int fo = 0; fo < FOUT; ++fo) outf[(size_t)node * FOUT + fo] = o[fo];
    }
}

// ---------------- launch ----------------

extern "C" void kernel_launch(void* const* d_in, const int* in_sizes, int n_in,
                              void* d_out, int out_size, void* d_ws, size_t ws_size,
                              hipStream_t stream) {
    const float* x  = (const float*)d_in[0];
    const int*   ei = (const int*)d_in[1];
    const float* W1 = (const float*)d_in[2];
    const float* b1 = (const float*)d_in[3];
    const float* W2 = (const float*)d_in[4];
    const float* b2 = (const float*)d_in[5];
    const float* W3 = (const float*)d_in[6];
    const float* b3 = (const float*)d_in[7];
    float* out = (float*)d_out;

    const int n = in_sizes[0] / 11;   // 100000
    const int E = in_sizes[1] / 2;    // 3200000
    const int* src = ei;
    const int* dst = ei + E;

    const int nbkt = (n + NPB - 1) >> NPB_SHIFT;        // 782
    const int HBr  = (E + CHUNK - 1) / CHUNK;           // 391
    const size_t len = (size_t)nbkt * HBr;              // 305,762
    const int nb = (int)((len + 8191) / 8192);          // 38 (<=64)

    char* ws = (char*)d_ws;
    size_t off = 0;
    auto alloc = [&](size_t bytes) {
        void* p = ws + off;
        off = (off + bytes + 255) & ~(size_t)255;
        return p;
    };
    int*      offbuf    = (int*)     alloc(len * 4);
    int*      partial   = (int*)     alloc((size_t)128 * 4);
    int*      ebuf      = (int*)     alloc((size_t)E * 4);
    int*      csr_src   = (int*)     alloc((size_t)E * 4);
    int*      row_start = (int*)     alloc((size_t)(n + 1) * 4);
    float*    dinv      = (float*)   alloc((size_t)n * 4);
    unsigned* g0h       = (unsigned*)alloc((size_t)n * 16 * 2);   // fp16 tables
    unsigned* g1h       = (unsigned*)alloc((size_t)n * 16 * 2);
    unsigned* g2h       = (unsigned*)alloc((size_t)n * 32 * 2);
    float*    preS      = (float*)   alloc((size_t)n * 16 * 4);   // pre1 / pre2
    float*    preL      = (float*)   alloc((size_t)n * 32 * 4);   // pre3
    (void)ws_size;

    const int B = 256;
    int gn   = (n + B - 1) / B;
    int gagg = (n + 15) / 16;         // 4 waves/block x 4 nodes/wave

    // ---- atomic-free CSR build (+ fused dinv/row_start/pad_scale->fp16) ----
    hist_kernel<<<HBr, 512, 0, stream>>>(dst, offbuf, E, HBr, nbkt);
    scan_block8_kernel<<<nb, 1024, 0, stream>>>(offbuf, partial, (int)len);
    scatter_kernel<<<HBr, 512, 0, stream>>>(src, dst, offbuf, partial, ebuf, E, HBr, nbkt, nb);
    bucket_build_kernel<<<nbkt, 512, 0, stream>>>(ebuf, offbuf, partial, x, csr_src, row_start,
                                                  dinv, g0h, E, HBr, nbkt, n, nb);

    // layer 1: agg(16-wide fp16) -> linear 11->16, relu, scale -> fp16 table
    aggregate_kernel<16><<<gagg, B, 0, stream>>>((const uint2*)g0h, row_start, csr_src, dinv,
                                                 (float4*)preS, n);
    linear_kernel<16, 11, 16, true, true, true><<<gn, B, 0, stream>>>(preS, W1, b1, dinv, g1h, n);

    // layer 2: agg(16 fp16) -> linear 16->32, relu, scale -> fp16 table
    aggregate_kernel<16><<<gagg, B, 0, stream>>>((const uint2*)g1h, row_start, csr_src, dinv,
                                                 (float4*)preS, n);
    linear_kernel<16, 16, 32, true, true, true><<<gn, B, 0, stream>>>(preS, W2, b2, dinv, g2h, n);

    // layer 3: agg(32 fp16) -> linear 32->64, no relu, no scale, fp32 out
    aggregate_kernel<32><<<gagg, B, 0, stream>>>((const uint2*)g2h, row_start, csr_src, dinv,
                                                 (float4*)preL, n);
    linear_kernel<32, 32, 64, false, false, false><<<gn, B, 0, stream>>>(preL, W3, b3, dinv, out, n);
}